// Round 1
// baseline (749.556 us; speedup 1.0000x reference)
//
#include <hip/hip_runtime.h>

// Deformable conv2d: N=4, C=256, OC=256, H=W=80, 3x3, stride=1, pad=1, dil=1.
// Fused im2col(bilinear)+GEMM. fp32 throughout (no fp32 MFMA on CDNA4; this
// round targets correctness + VALU-bound structure; bf16/MFMA is the next lever).

#define Cc   256
#define OCc  256
#define Hh   80
#define Ww   80
#define HW   6400
#define KK   9
#define PT   32          // pixels per block tile
#define CCH  16          // input channels per K-chunk
#define CKL  (CCH * KK)  // 144 K-slice per chunk

__global__ __launch_bounds__(256, 4) void dcn_fused(
    const float* __restrict__ x, const float* __restrict__ offset,
    const float* __restrict__ weight, float* __restrict__ out) {
  // Sampled column slab for the current channel chunk: [144][32] floats = 18 KB
  __shared__ float s_col[CKL][PT];
  // Per-(tap, pixel) bilinear corner weights & indices (channel-independent)
  __shared__ float4 s_w[KK * PT];   // 4.5 KB
  __shared__ int4   s_i[KK * PT];   // 4.5 KB

  const int tid = threadIdx.x;
  const int n  = blockIdx.y;
  const int p0 = blockIdx.x * PT;

  // ---- Phase 0: bilinear coordinate precompute (once per block) ----
  for (int s = tid; s < KK * PT; s += 256) {
    const int k = s / PT, p = s % PT;
    const int pp = p0 + p;
    const int oy = pp / Ww, ox = pp % Ww;
    const int ky = k / 3, kx = k % 3;
    // offset layout: channel = 2*k (y), 2*k+1 (x)
    const float offy = offset[(size_t)(n * 18 + 2 * k    ) * HW + pp];
    const float offx = offset[(size_t)(n * 18 + 2 * k + 1) * HW + pp];
    const float py = offy + (float)(ky + oy - 1);
    const float px = offx + (float)(kx + ox - 1);
    const float fy0 = floorf(py), fx0 = floorf(px);
    const int iy0 = (int)fy0, ix0 = (int)fx0;
    const float wy1 = py - fy0, wx1 = px - fx0;
    const float wy0 = 1.f - wy1, wx0 = 1.f - wx1;
    const bool my0 = (iy0     >= 0) & (iy0     < Hh);
    const bool my1 = (iy0 + 1 >= 0) & (iy0 + 1 < Hh);
    const bool mx0 = (ix0     >= 0) & (ix0     < Ww);
    const bool mx1 = (ix0 + 1 >= 0) & (ix0 + 1 < Ww);
    const int cy0 = min(max(iy0,     0), Hh - 1);
    const int cy1 = min(max(iy0 + 1, 0), Hh - 1);
    const int cx0 = min(max(ix0,     0), Ww - 1);
    const int cx1 = min(max(ix0 + 1, 0), Ww - 1);
    float4 w4;
    w4.x = wx0 * wy0 * ((my0 && mx0) ? 1.f : 0.f);
    w4.y = wx1 * wy0 * ((my0 && mx1) ? 1.f : 0.f);
    w4.z = wx0 * wy1 * ((my1 && mx0) ? 1.f : 0.f);
    w4.w = wx1 * wy1 * ((my1 && mx1) ? 1.f : 0.f);
    int4 i4;
    i4.x = cy0 * Ww + cx0;  i4.y = cy0 * Ww + cx1;
    i4.z = cy1 * Ww + cx0;  i4.w = cy1 * Ww + cx1;
    s_w[s] = w4;
    s_i[s] = i4;
  }

  float acc[PT];
  #pragma unroll
  for (int p = 0; p < PT; ++p) acc[p] = 0.f;

  const float* wrow = weight + (size_t)tid * (Cc * KK);  // thread owns oc = tid
  __syncthreads();

  // ---- Main loop over input-channel chunks ----
  for (int c0 = 0; c0 < Cc; c0 += CCH) {
    // Stage sampled columns: 144 x 32 values, 18 samples/thread
    for (int s = tid; s < CKL * PT; s += 256) {
      const int ckl = s / PT, p = s % PT;
      const int cl = ckl / KK, k = ckl % KK;
      const float* xp = x + (size_t)(n * Cc + c0 + cl) * HW;
      const int kp = k * PT + p;
      const float4 w4 = s_w[kp];
      const int4   i4 = s_i[kp];
      s_col[ckl][p] = w4.x * xp[i4.x] + w4.y * xp[i4.y]
                    + w4.z * xp[i4.z] + w4.w * xp[i4.w];
    }
    __syncthreads();

    // Rank-144 update: each thread = one oc row, 32 pixel accumulators
    const float* wr = wrow + (size_t)c0 * KK;
    #pragma unroll 1
    for (int ck4 = 0; ck4 < CKL / 4; ++ck4) {
      const float4 w4 = *(const float4*)(wr + ck4 * 4);
      #pragma unroll
      for (int j = 0; j < 4; ++j) {
        const float w = (&w4.x)[j];
        const float4* col4 = (const float4*)s_col[ck4 * 4 + j];
        #pragma unroll
        for (int q = 0; q < PT / 4; ++q) {
          const float4 v = col4[q];  // broadcast read (uniform addr) — conflict-free
          acc[q * 4 + 0] += w * v.x;
          acc[q * 4 + 1] += w * v.y;
          acc[q * 4 + 2] += w * v.z;
          acc[q * 4 + 3] += w * v.w;
        }
      }
    }
    __syncthreads();
  }

  // ---- Epilogue: store 32 pixels for oc = tid ----
  float* op = out + (size_t)(n * OCc + tid) * HW + p0;
  #pragma unroll
  for (int q = 0; q < PT / 4; ++q) {
    float4 v = make_float4(acc[q * 4 + 0], acc[q * 4 + 1],
                           acc[q * 4 + 2], acc[q * 4 + 3]);
    *(float4*)(op + q * 4) = v;
  }
}

extern "C" void kernel_launch(void* const* d_in, const int* in_sizes, int n_in,
                              void* d_out, int out_size, void* d_ws, size_t ws_size,
                              hipStream_t stream) {
  const float* x      = (const float*)d_in[0];
  const float* offset = (const float*)d_in[1];
  const float* weight = (const float*)d_in[2];
  float* out = (float*)d_out;

  dim3 grid(HW / PT, 4);   // 200 pixel tiles x 4 batches = 800 blocks
  dim3 block(256);
  dcn_fused<<<grid, block, 0, stream>>>(x, offset, weight, out);
}

// Round 2
// 277.186 us; speedup vs baseline: 2.7042x; 2.7042x over previous
//
#include <hip/hip_runtime.h>

// Deformable conv2d (N=4, C=OC=256, 80x80, 3x3, s1 p1 d1) via fused
// bilinear-im2col + bf16 MFMA GEMM (fp32 accumulate).
//
// Kernel 1: pack weight fp32 -> bf16 in MFMA A-fragment order (d_ws, 1.18MB).
// Kernel 2: per block = 32 pixels x all 256 oc; loop K=2304 in chunks of 64:
//   sample 64x32 bilinear values -> XOR-swizzled LDS slab -> 16x16x32 bf16 MFMA.

typedef short short8 __attribute__((ext_vector_type(8)));
typedef float floatx4 __attribute__((ext_vector_type(4)));

#define Cc    256
#define OCc   256
#define Hh    80
#define Ww    80
#define HW    6400
#define KK    9
#define Ktot  2304          // Cc * KK
#define PT    32            // pixels per block
#define KC    64            // K elements per chunk
#define NCHUNK (Ktot / KC)  // 36
#define NKB   (Ktot / 32)   // 72 MFMA k-steps total

__device__ __forceinline__ unsigned short f2bf(float f) {
  unsigned u = __float_as_uint(f);
  u += 0x7FFF + ((u >> 16) & 1);   // round-to-nearest-even
  return (unsigned short)(u >> 16);
}

// ---- Kernel 1: weight fp32 -> bf16, fragment-ordered ----
// Packed index: ((kb*16 + ocf)*64 + lane)*8 + e  maps to
// weight[oc = ocf*16 + (lane&15)][k = kb*32 + (lane>>4)*8 + e]
__global__ void pack_weight(const float* __restrict__ w,
                            unsigned short* __restrict__ wp) {
  const int t = blockIdx.x * 256 + threadIdx.x;   // 72*16*64 = 73728 threads
  const int lane = t & 63;
  const int ocf  = (t >> 6) & 15;
  const int kb   = t >> 10;                       // 0..71
  const int oc   = ocf * 16 + (lane & 15);
  const int k0   = kb * 32 + (lane >> 4) * 8;
  const float* src = w + (size_t)oc * Ktot + k0;
  unsigned short v[8];
  #pragma unroll
  for (int e = 0; e < 8; ++e) v[e] = f2bf(src[e]);
  short8 pk;
  #pragma unroll
  for (int e = 0; e < 8; ++e) pk[e] = (short)v[e];
  *(short8*)(wp + (size_t)t * 8) = pk;            // coalesced 16B/lane
}

// ---- Kernel 2: fused sampling + MFMA GEMM ----
__global__ __launch_bounds__(256, 4) void dcn_mfma(
    const float* __restrict__ x, const float* __restrict__ offset,
    const unsigned short* __restrict__ wp, float* __restrict__ out) {
  __shared__ unsigned short s_col[PT * KC];  // 4KB, XOR-swizzled [px][k]
  __shared__ float4 s_w[KK * PT];            // bilinear corner weights
  __shared__ int4   s_i[KK * PT];            // bilinear corner indices

  const int tid  = threadIdx.x;
  const int lane = tid & 63;
  const int wv   = tid >> 6;        // wave 0..3 -> oc rows [wv*64, wv*64+64)
  const int n    = blockIdx.y;
  const int p0   = blockIdx.x * PT;

  // ---- Phase 0: bilinear coordinates (per tap x pixel; channel-independent)
  for (int s = tid; s < KK * PT; s += 256) {
    const int k = s / PT, p = s % PT;
    const int pp = p0 + p;
    const int oy = pp / Ww, ox = pp % Ww;
    const int ky = k / 3, kx = k % 3;
    const float offy = offset[(size_t)(n * 18 + 2 * k    ) * HW + pp];
    const float offx = offset[(size_t)(n * 18 + 2 * k + 1) * HW + pp];
    const float py = offy + (float)(ky + oy - 1);
    const float px = offx + (float)(kx + ox - 1);
    const float fy0 = floorf(py), fx0 = floorf(px);
    const int iy0 = (int)fy0, ix0 = (int)fx0;
    const float wy1 = py - fy0, wx1 = px - fx0;
    const float wy0 = 1.f - wy1, wx0 = 1.f - wx1;
    const bool my0 = (iy0     >= 0) & (iy0     < Hh);
    const bool my1 = (iy0 + 1 >= 0) & (iy0 + 1 < Hh);
    const bool mx0 = (ix0     >= 0) & (ix0     < Ww);
    const bool mx1 = (ix0 + 1 >= 0) & (ix0 + 1 < Ww);
    const int cy0 = min(max(iy0,     0), Hh - 1);
    const int cy1 = min(max(iy0 + 1, 0), Hh - 1);
    const int cx0 = min(max(ix0,     0), Ww - 1);
    const int cx1 = min(max(ix0 + 1, 0), Ww - 1);
    float4 w4;
    w4.x = wx0 * wy0 * ((my0 && mx0) ? 1.f : 0.f);
    w4.y = wx1 * wy0 * ((my0 && mx1) ? 1.f : 0.f);
    w4.z = wx0 * wy1 * ((my1 && mx0) ? 1.f : 0.f);
    w4.w = wx1 * wy1 * ((my1 && mx1) ? 1.f : 0.f);
    int4 i4;
    i4.x = cy0 * Ww + cx0;  i4.y = cy0 * Ww + cx1;
    i4.z = cy1 * Ww + cx0;  i4.w = cy1 * Ww + cx1;
    s_w[s] = w4;
    s_i[s] = i4;
  }

  floatx4 acc[4][2] = {};           // 4 oc-frags x 2 px-frags, fp32
  __syncthreads();

  const int lm = lane & 15, lg = lane >> 4;
  const int spx  = tid & 31;        // sampling: pixel (lane-inner -> coalesced)
  const int skc0 = tid >> 5;        // sampling: k within chunk, +8 per iter

  for (int ch = 0; ch < NCHUNK; ++ch) {
    const int c0 = ch * KC;
    // ---- sampling: 64k x 32px -> swizzled LDS ----
    #pragma unroll
    for (int i = 0; i < (KC * PT) / 256; ++i) {     // 8 samples/thread
      const int kc  = skc0 + i * 8;
      const int kg  = c0 + kc;                      // global K index = c*9 + tap
      const int c   = kg / 9;
      const int tap = kg - c * 9;
      const float4 w4 = s_w[tap * PT + spx];
      const int4   i4 = s_i[tap * PT + spx];
      const float* xp = x + (size_t)(n * Cc + c) * HW;
      const float v = w4.x * xp[i4.x] + w4.y * xp[i4.y]
                    + w4.z * xp[i4.z] + w4.w * xp[i4.w];
      const int byte = spx * 128 + ((kc * 2) ^ ((spx & 7) << 4));
      *(unsigned short*)((char*)s_col + byte) = f2bf(v);
    }
    __syncthreads();

    // ---- MFMA: 2 k-steps x (4 oc-frags x 2 px-frags) ----
    const int kb0 = ch * 2;
    #pragma unroll
    for (int ks = 0; ks < 2; ++ks) {
      short8 b[2];
      #pragma unroll
      for (int j = 0; j < 2; ++j) {
        const int px = j * 16 + lm;
        const int byte = px * 128 + (((ks * 64) + lg * 16) ^ ((px & 7) << 4));
        b[j] = *(const short8*)((const char*)s_col + byte);  // ds_read_b128
      }
      const size_t abase = (size_t)(kb0 + ks) * 16 * 64 * 8;
      #pragma unroll
      for (int f = 0; f < 4; ++f) {
        const int ocf = wv * 4 + f;
        const short8 a = *(const short8*)(wp + abase + (size_t)(ocf * 64 + lane) * 8);
        acc[f][0] = __builtin_amdgcn_mfma_f32_16x16x32_bf16(a, b[0], acc[f][0], 0, 0, 0);
        acc[f][1] = __builtin_amdgcn_mfma_f32_16x16x32_bf16(a, b[1], acc[f][1], 0, 0, 0);
      }
    }
    __syncthreads();
  }

  // ---- epilogue: C/D layout col=lane&15 (px), row=(lane>>4)*4+r (oc) ----
  #pragma unroll
  for (int f = 0; f < 4; ++f) {
    const int oc = wv * 64 + f * 16 + lg * 4;
    #pragma unroll
    for (int j = 0; j < 2; ++j) {
      const int px = p0 + j * 16 + lm;
      #pragma unroll
      for (int r = 0; r < 4; ++r) {
        out[(size_t)(n * OCc + oc + r) * HW + px] = acc[f][j][r];
      }
    }
  }
}

extern "C" void kernel_launch(void* const* d_in, const int* in_sizes, int n_in,
                              void* d_out, int out_size, void* d_ws, size_t ws_size,
                              hipStream_t stream) {
  const float* x      = (const float*)d_in[0];
  const float* offset = (const float*)d_in[1];
  const float* weight = (const float*)d_in[2];
  float* out = (float*)d_out;
  unsigned short* wp = (unsigned short*)d_ws;   // 589824 * 2B = 1.18 MB

  pack_weight<<<dim3(NKB * 16 * 64 / 256), dim3(256), 0, stream>>>(weight, wp);
  dcn_mfma<<<dim3(HW / PT, 4), dim3(256), 0, stream>>>(x, offset, wp, out);
}

// Round 3
// 168.055 us; speedup vs baseline: 4.4602x; 1.6494x over previous
//
#include <hip/hip_runtime.h>

// Deformable conv2d (N=4, C=OC=256, 80x80, 3x3, s1 p1 d1):
// fused bilinear-im2col + bf16 MFMA GEMM, fp32 accumulate.
// R3: paired-corner dwordx2 gathers (2 loads/sample, weights pre-swapped for
// edge clamp), double-buffered LDS chunk pipeline (issue gathers -> MFMA ->
// bilinear+pack+ds_write_b128), one barrier per chunk.

typedef short short8 __attribute__((ext_vector_type(8)));
typedef float floatx4 __attribute__((ext_vector_type(4)));
typedef float floatx2 __attribute__((ext_vector_type(2)));

#define Cc    256
#define OCc   256
#define Hh    80
#define Ww    80
#define HW    6400
#define KK    9
#define Ktot  2304
#define PT    32            // pixels per block
#define KC    64            // K per chunk
#define NCHUNK (Ktot / KC)  // 36
#define NKB   (Ktot / 32)   // 72

__device__ __forceinline__ unsigned short f2bf(float f) {
  unsigned u = __float_as_uint(f);
  u += 0x7FFF + ((u >> 16) & 1);
  return (unsigned short)(u >> 16);
}

// ---- Kernel 1: weight fp32 -> bf16 in MFMA A-fragment order ----
__global__ void pack_weight(const float* __restrict__ w,
                            unsigned short* __restrict__ wp) {
  const int t = blockIdx.x * 256 + threadIdx.x;   // 73728 threads
  const int lane = t & 63;
  const int ocf  = (t >> 6) & 15;
  const int kb   = t >> 10;
  const int oc   = ocf * 16 + (lane & 15);
  const int k0   = kb * 32 + (lane >> 4) * 8;
  const float* src = w + (size_t)oc * Ktot + k0;
  short8 pk;
  #pragma unroll
  for (int e = 0; e < 8; ++e) pk[e] = (short)f2bf(src[e]);
  *(short8*)(wp + (size_t)t * 8) = pk;
}

// ---- Kernel 2: fused sampling + MFMA ----
__global__ __launch_bounds__(256, 3) void dcn_mfma(
    const float* __restrict__ x, const float* __restrict__ offset,
    const unsigned short* __restrict__ wp, float* __restrict__ out) {
  __shared__ unsigned short s_col[2][PT * KC];  // 2 x 4KB, XOR-swizzled [px][k]
  __shared__ float4 s_w[KK * PT];               // corner weights (pre-swapped)
  __shared__ int2   s_i[KK * PT];               // row-base offsets (y0,y1)

  const int tid  = threadIdx.x;
  const int lane = tid & 63;
  const int wv   = tid >> 6;
  const int n    = blockIdx.y;
  const int p0   = blockIdx.x * PT;

  // ---- Phase 0: bilinear coords; fold edge handling into the weights ----
  for (int s = tid; s < KK * PT; s += 256) {
    const int k = s / PT, p = s % PT;
    const int pp = p0 + p;
    const int oy = pp / Ww, ox = pp % Ww;
    const int ky = k / 3, kx = k % 3;
    const float offy = offset[(size_t)(n * 18 + 2 * k    ) * HW + pp];
    const float offx = offset[(size_t)(n * 18 + 2 * k + 1) * HW + pp];
    const float py = offy + (float)(ky + oy - 1);
    const float px = offx + (float)(kx + ox - 1);
    const float fy0 = floorf(py), fx0 = floorf(px);
    const int iy0 = (int)fy0, ix0 = (int)fx0;
    const float wy1 = py - fy0, wx1 = px - fx0;
    const float wy0 = 1.f - wy1, wx0 = 1.f - wx1;
    const bool my0 = (iy0     >= 0) & (iy0     < Hh);
    const bool my1 = (iy0 + 1 >= 0) & (iy0 + 1 < Hh);
    const bool mx0 = (ix0     >= 0) & (ix0     < Ww);
    const bool mx1 = (ix0 + 1 >= 0) & (ix0 + 1 < Ww);
    const int cy0 = min(max(iy0,     0), Hh - 1);
    const int cy1 = min(max(iy0 + 1, 0), Hh - 1);
    const int bx  = min(max(ix0, 0), Ww - 2);   // dwordx2 base: [bx, bx+1]
    const bool sel = (ix0 == bx);               // x0 maps to f2.x ?
    const float wa = wx0 * wy0 * ((my0 && mx0) ? 1.f : 0.f);
    const float wb = wx1 * wy0 * ((my0 && mx1) ? 1.f : 0.f);
    const float wc = wx0 * wy1 * ((my1 && mx0) ? 1.f : 0.f);
    const float wd = wx1 * wy1 * ((my1 && mx1) ? 1.f : 0.f);
    float4 w4;  // if x0 clamped off-base, swap pair weights (masks make exact)
    w4.x = sel ? wa : wb;  w4.y = sel ? wb : wa;
    w4.z = sel ? wc : wd;  w4.w = sel ? wd : wc;
    s_w[s] = w4;
    s_i[s] = make_int2(cy0 * Ww + bx, cy1 * Ww + bx);
  }

  floatx4 acc[4][2] = {};
  const int lm = lane & 15, lg = lane >> 4;
  const int spx  = tid & 31;        // sampling pixel
  const int skc0 = (tid >> 5) * 8;  // 8 consecutive k per thread
  __syncthreads();

  // ---- Prologue: sample chunk 0 into buffer 0 ----
  {
    floatx2 ga[8], gb[8];
    #pragma unroll
    for (int i = 0; i < 8; ++i) {
      const int kg = skc0 + i;
      const int c = kg / 9, tap = kg - c * 9;
      const int2 o2 = s_i[tap * PT + spx];
      const float* xp = x + (size_t)(n * Cc + c) * HW;
      ga[i] = *(const floatx2*)(xp + o2.x);
      gb[i] = *(const floatx2*)(xp + o2.y);
    }
    short8 pk;
    #pragma unroll
    for (int i = 0; i < 8; ++i) {
      const int kg = skc0 + i;
      const int c = kg / 9, tap = kg - c * 9;
      const float4 w4 = s_w[tap * PT + spx];
      const float v = w4.x * ga[i].x + w4.y * ga[i].y
                    + w4.z * gb[i].x + w4.w * gb[i].y;
      pk[i] = (short)f2bf(v);
    }
    const int byte = spx * 128 + ((skc0 * 2) ^ ((spx & 7) << 4));
    *(short8*)((char*)s_col[0] + byte) = pk;
  }
  __syncthreads();

  // ---- Main pipeline ----
  for (int ch = 0; ch < NCHUNK; ++ch) {
    const int cur = ch & 1;
    const bool more = (ch + 1 < NCHUNK);

    // 1) issue next chunk's gathers -> registers (latency hides under MFMA)
    floatx2 ga[8], gb[8];
    if (more) {
      const int c0n = (ch + 1) * KC;
      #pragma unroll
      for (int i = 0; i < 8; ++i) {
        const int kg = c0n + skc0 + i;
        const int c = kg / 9, tap = kg - c * 9;
        const int2 o2 = s_i[tap * PT + spx];
        const float* xp = x + (size_t)(n * Cc + c) * HW;
        ga[i] = *(const floatx2*)(xp + o2.x);
        gb[i] = *(const floatx2*)(xp + o2.y);
      }
    }

    // 2) MFMA on current buffer
    const int kb0 = ch * 2;
    #pragma unroll
    for (int ks = 0; ks < 2; ++ks) {
      short8 b[2];
      #pragma unroll
      for (int j = 0; j < 2; ++j) {
        const int px = j * 16 + lm;
        const int byte = px * 128 + (((ks * 64) + lg * 16) ^ ((px & 7) << 4));
        b[j] = *(const short8*)((const char*)s_col[cur] + byte);
      }
      const size_t abase = (size_t)(kb0 + ks) * 16 * 64 * 8;
      #pragma unroll
      for (int f = 0; f < 4; ++f) {
        const int ocf = wv * 4 + f;
        const short8 a = *(const short8*)(wp + abase + (size_t)(ocf * 64 + lane) * 8);
        acc[f][0] = __builtin_amdgcn_mfma_f32_16x16x32_bf16(a, b[0], acc[f][0], 0, 0, 0);
        acc[f][1] = __builtin_amdgcn_mfma_f32_16x16x32_bf16(a, b[1], acc[f][1], 0, 0, 0);
      }
    }

    // 3) bilinear + pack + single b128 write into the other buffer
    if (more) {
      const int c0n = (ch + 1) * KC;
      short8 pk;
      #pragma unroll
      for (int i = 0; i < 8; ++i) {
        const int kg = c0n + skc0 + i;
        const int c = kg / 9, tap = kg - c * 9;
        const float4 w4 = s_w[tap * PT + spx];
        const float v = w4.x * ga[i].x + w4.y * ga[i].y
                      + w4.z * gb[i].x + w4.w * gb[i].y;
        pk[i] = (short)f2bf(v);
      }
      const int byte = spx * 128 + ((skc0 * 2) ^ ((spx & 7) << 4));
      *(short8*)((char*)s_col[cur ^ 1] + byte) = pk;
    }
    __syncthreads();
  }

  // ---- Epilogue: C/D layout col(px)=lane&15, row(oc)=(lane>>4)*4+r ----
  #pragma unroll
  for (int f = 0; f < 4; ++f) {
    const int oc = wv * 64 + f * 16 + lg * 4;
    #pragma unroll
    for (int j = 0; j < 2; ++j) {
      const int px = p0 + j * 16 + lm;
      #pragma unroll
      for (int r = 0; r < 4; ++r) {
        out[(size_t)(n * OCc + oc + r) * HW + px] = acc[f][j][r];
      }
    }
  }
}

extern "C" void kernel_launch(void* const* d_in, const int* in_sizes, int n_in,
                              void* d_out, int out_size, void* d_ws, size_t ws_size,
                              hipStream_t stream) {
  const float* x      = (const float*)d_in[0];
  const float* offset = (const float*)d_in[1];
  const float* weight = (const float*)d_in[2];
  float* out = (float*)d_out;
  unsigned short* wp = (unsigned short*)d_ws;

  pack_weight<<<dim3(NKB * 16 * 64 / 256), dim3(256), 0, stream>>>(weight, wp);
  dcn_mfma<<<dim3(HW / PT, 4), dim3(256), 0, stream>>>(x, offset, wp, out);
}